// Round 3
// baseline (11915.830 us; speedup 1.0000x reference)
//
#include <hip/hip_runtime.h>
#include <hip/hip_bf16.h>

#define NT 256          // threads per block
#define RT 16           // rows per block
#define AP 17           // activation LDS pitch (floats): act[col][AP] transposed, pitch 17 kills bank conflicts
#define WP 516          // weight-tile LDS pitch (floats): 512 + 4 keeps float4 alignment and spreads banks
#define INN 256
#define HIDN 512
#define LATN 256
#define KCB 1024
#define BROWS 131072

// d_out element offsets (fp32 elements)
#define SC_OFF   33554432ull            // B*LAT
#define RS_OFF   33685504ull
#define LOSS_OFF 33816576ull
#define IDS_OFF  33816577ull

// ---------------------------------------------------------------------------
// Tiled fp32 GEMM layer: act (transposed [col][row], pitch AP) -> act in-place.
// Accumulation: single accumulator per output, ascending-k FMA chain — matches
// BLAS sgemm micro-kernel rounding so zl tracks the numpy reference ~bit-exactly.
// ---------------------------------------------------------------------------
template<int CPER>
__device__ __forceinline__ void gemm_layer(float* act, float* wbuf,
    const float* __restrict__ W, const float* __restrict__ bias,
    const int K, const bool do_relu, const int tid)
{
    constexpr int NCOLS = CPER * 64;
    const int rgrp = tid & 3;
    const int c0   = (tid >> 2) * CPER;

    float acc[4][CPER];
#pragma unroll
    for (int i = 0; i < 4; ++i)
#pragma unroll
        for (int m = 0; m < CPER; ++m) acc[i][m] = 0.f;

    const int ntiles = K >> 3;
    for (int kt = 0; kt < ntiles; ++kt) {
        __syncthreads();
        // stage W tile: wbuf[kk][j] = W[j][kt*8+kk]
#pragma unroll
        for (int e = 0; e < (NCOLS * 8) / NT; ++e) {
            const int idx = tid + e * NT;
            const int j = idx >> 3, kk = idx & 7;
            wbuf[kk * WP + j] = W[(size_t)j * K + (kt << 3) + kk];
        }
        __syncthreads();
#pragma unroll
        for (int kk = 0; kk < 8; ++kk) {
            const int ka = (kt << 3) + kk;
            const float a0 = act[ka * AP + rgrp];
            const float a1 = act[ka * AP + rgrp + 4];
            const float a2 = act[ka * AP + rgrp + 8];
            const float a3 = act[ka * AP + rgrp + 12];
            const float* wr = &wbuf[kk * WP + c0];
#pragma unroll
            for (int q = 0; q < CPER / 4; ++q) {
                const float4 wv = *(const float4*)(wr + 4 * q);
                const float wz[4] = {wv.x, wv.y, wv.z, wv.w};
#pragma unroll
                for (int t = 0; t < 4; ++t) {
                    const float w = wz[t];
                    acc[0][4 * q + t] = fmaf(a0, w, acc[0][4 * q + t]);
                    acc[1][4 * q + t] = fmaf(a1, w, acc[1][4 * q + t]);
                    acc[2][4 * q + t] = fmaf(a2, w, acc[2][4 * q + t]);
                    acc[3][4 * q + t] = fmaf(a3, w, acc[3][4 * q + t]);
                }
            }
        }
    }
    __syncthreads();   // all reads of act done before overwriting
#pragma unroll
    for (int m = 0; m < CPER; ++m) {
        const float bv = bias[c0 + m];
#pragma unroll
        for (int i = 0; i < 4; ++i) {
            float v = __fadd_rn(acc[i][m], bv);   // single rounded add, like np G+b
            if (do_relu) v = fmaxf(v, 0.f);
            act[(c0 + m) * AP + rgrp + 4 * i] = v;
        }
    }
    __syncthreads();
}

// numpy pairwise sum of squares over 256 contiguous elements:
// split 128+128; each 128-block: 8 accumulators, unrolled-by-8, combined
// ((r0+r1)+(r2+r3))+((r4+r5)+(r6+r7)); halves added last. Squares rounded
// separately (no FMA) — replicates np.sum(z*z, axis=1) rounding.
__device__ __forceinline__ float np_sumsq_row(const float* act, const int r)
{
    float half[2];
#pragma unroll
    for (int h = 0; h < 2; ++h) {
        const int base = h * 128;
        float rr[8];
#pragma unroll
        for (int j = 0; j < 8; ++j) {
            const float v = act[(base + j) * AP + r];
            rr[j] = __fmul_rn(v, v);
        }
        for (int i = 8; i < 128; i += 8) {
#pragma unroll
            for (int j = 0; j < 8; ++j) {
                const float v = act[(base + i + j) * AP + r];
                rr[j] = __fadd_rn(rr[j], __fmul_rn(v, v));
            }
        }
        half[h] = __fadd_rn(
            __fadd_rn(__fadd_rn(rr[0], rr[1]), __fadd_rn(rr[2], rr[3])),
            __fadd_rn(__fadd_rn(rr[4], rr[5]), __fadd_rn(rr[6], rr[7])));
    }
    return __fadd_rn(half[0], half[1]);
}

// ---------------------------------------------------------------------------
// NET: 0 = decoder (+VQ distance/argmin/outputs/loss), 1 = scaler, 2 = redshift
// ---------------------------------------------------------------------------
template<int NET>
__global__ __launch_bounds__(NT, 3)
void net_kernel(const float* __restrict__ z,
                const float* __restrict__ W0, const float* __restrict__ b0,
                const float* __restrict__ W1, const float* __restrict__ b1,
                const float* __restrict__ Wo, const float* __restrict__ bo,
                const float* __restrict__ cb, const float* __restrict__ cbn,
                float* __restrict__ loss_ws,
                float* __restrict__ out)
{
    __shared__ __align__(16) float act[HIDN * AP];   // 34816 B
    __shared__ __align__(16) float wbuf[8 * WP];     // 16512 B
    __shared__ int idT[RT];
    __shared__ float sz2[RT];

    const int tid  = threadIdx.x;
    const int row0 = blockIdx.x * RT;

    // stage z tile transposed: act[c][r]
#pragma unroll
    for (int it = 0; it < RT; ++it)
        act[tid * AP + it] = z[(size_t)(row0 + it) * INN + tid];

    gemm_layer<8>(act, wbuf, W0, b0, INN,  true, tid);
    gemm_layer<8>(act, wbuf, W1, b1, HIDN, true, tid);

    if (NET == 0) {
        gemm_layer<4>(act, wbuf, Wo, bo, HIDN, false, tid);   // zl -> act[c][r], c<256

        // per-row sum(zl^2) with numpy-pairwise rounding
        if (tid < RT) sz2[tid] = np_sumsq_row(act, tid);
        __syncthreads();

        // ---- VQ distance, replicating np fp32 rounding:
        //      d2 = fl( fl(sumz2 - fl(2*dot)) + cn )
        const int rgrp = tid & 3;
        const int kgrp = tid >> 2;          // 64 k-groups x 8 k each per half
        float bestv[4] = {1e30f, 1e30f, 1e30f, 1e30f};
        int   bestk[4] = {0, 0, 0, 0};

        for (int kh = 0; kh < 2; ++kh) {
            float s[4][8];
#pragma unroll
            for (int i = 0; i < 4; ++i)
#pragma unroll
                for (int m = 0; m < 8; ++m) s[i][m] = 0.f;

            for (int ct = 0; ct < 32; ++ct) {
                __syncthreads();
                // stage cb tile [8 c][512 k] (float4, coalesced)
#pragma unroll
                for (int e = 0; e < 4; ++e) {
                    const int idx = tid + e * NT;
                    const int cc = idx >> 7, k4 = (idx & 127) << 2;
                    *(float4*)&wbuf[cc * WP + k4] =
                        *(const float4*)&cb[(size_t)(ct * 8 + cc) * KCB + (kh << 9) + k4];
                }
                __syncthreads();
#pragma unroll
                for (int cc = 0; cc < 8; ++cc) {
                    const int ca = ct * 8 + cc;
                    const float a0 = act[ca * AP + rgrp];
                    const float a1 = act[ca * AP + rgrp + 4];
                    const float a2 = act[ca * AP + rgrp + 8];
                    const float a3 = act[ca * AP + rgrp + 12];
                    const float* cr = &wbuf[cc * WP + (kgrp << 3)];
                    const float4 w0 = *(const float4*)cr;
                    const float4 w1 = *(const float4*)(cr + 4);
                    const float wz[8] = {w0.x, w0.y, w0.z, w0.w, w1.x, w1.y, w1.z, w1.w};
#pragma unroll
                    for (int m = 0; m < 8; ++m) {
                        s[0][m] = fmaf(a0, wz[m], s[0][m]);
                        s[1][m] = fmaf(a1, wz[m], s[1][m]);
                        s[2][m] = fmaf(a2, wz[m], s[2][m]);
                        s[3][m] = fmaf(a3, wz[m], s[3][m]);
                    }
                }
            }
            // fold into running argmin with np's exact rounding sequence
#pragma unroll
            for (int m = 0; m < 8; ++m) {
                const int kab = (kh << 9) + (kgrp << 3) + m;
                const float cn = cbn[kab];
#pragma unroll
                for (int i = 0; i < 4; ++i) {
                    const float t = __fsub_rn(sz2[rgrp + 4 * i],
                                              __fmul_rn(2.f, s[i][m]));
                    const float d = __fadd_rn(t, cn);
                    if (d < bestv[i]) { bestv[i] = d; bestk[i] = kab; }
                }
            }
        }

        // ---- cross-thread argmin reduce (wbuf reused as scratch)
        __syncthreads();
        float* rv = wbuf;
        int*   rk = (int*)(wbuf + 1024);
#pragma unroll
        for (int i = 0; i < 4; ++i) {
            rv[kgrp * 16 + rgrp + 4 * i] = bestv[i];
            rk[kgrp * 16 + rgrp + 4 * i] = bestk[i];
        }
        __syncthreads();
        if (tid < RT) {
            float bv = 1e30f; int bk = 0;
            for (int kg = 0; kg < 64; ++kg) {
                const float v = rv[kg * 16 + tid];
                const int   k = rk[kg * 16 + tid];
                if (v < bv || (v == bv && k < bk)) { bv = v; bk = k; }
            }
            idT[tid] = bk;
            out[IDS_OFF + row0 + tid] = (float)bk;
        }
        __syncthreads();

        // ---- epilogue: z_q_st = z_q (forward), loss partial
        float lsum = 0.f;
#pragma unroll
        for (int r = 0; r < RT; ++r) {
            const int id = idT[r];
            const float zv = act[tid * AP + r];
            const float q  = cb[(size_t)tid * KCB + id] - zv;
            out[(size_t)(row0 + r) * LATN + tid] = zv + q;
            lsum += q * q;
        }
        lsum += __shfl_down(lsum, 32);
        lsum += __shfl_down(lsum, 16);
        lsum += __shfl_down(lsum, 8);
        lsum += __shfl_down(lsum, 4);
        lsum += __shfl_down(lsum, 2);
        lsum += __shfl_down(lsum, 1);
        if ((tid & 63) == 0)
            atomicAdd(loss_ws, lsum * (1.0f / 33554432.0f));   // 1/(B*LAT)
    } else {
        // ---- out_dim == 1: out[r] = h2[r] . Wo + bo
        const int r  = tid & 15;
        const int kg = tid >> 4;
        float p = 0.f;
#pragma unroll
        for (int kk = 0; kk < 32; ++kk) {
            const int k = (kg << 5) + kk;
            p = fmaf(act[k * AP + r], Wo[k], p);
        }
        wbuf[kg * 16 + r] = p;
        __syncthreads();
        if (tid < RT) {
            float s2 = bo[0];
            for (int kg2 = 0; kg2 < 16; ++kg2) s2 += wbuf[kg2 * 16 + tid];
            if (NET == 2) s2 = fmaxf(s2, 0.f);
            const size_t off = (NET == 1) ? SC_OFF : RS_OFF;
            out[off + row0 + tid] = s2;
        }
    }
}

// cbnorm[k]: replicate np.sum(cb*cb, axis=0) — strided axis-0 reduction is
// SEQUENTIAL (no pairwise) over c ascending, squares rounded separately.
__global__ void prep_kernel(const float* __restrict__ cb, float* __restrict__ ws)
{
    const int k = blockIdx.x * NT + threadIdx.x;
    float a = 0.f;
    for (int c = 0; c < LATN; ++c) {
        const float v = cb[(size_t)c * KCB + k];
        a = __fadd_rn(a, __fmul_rn(v, v));
    }
    ws[k] = a;
    if (k == 0) ws[KCB] = 0.f;
}

__global__ void fin_kernel(const float* __restrict__ ws, float* __restrict__ out)
{
    if (threadIdx.x == 0) out[LOSS_OFF] = ws[KCB];
}

extern "C" void kernel_launch(void* const* d_in, const int* in_sizes, int n_in,
                              void* d_out, int out_size, void* d_ws, size_t ws_size,
                              hipStream_t stream)
{
    const float* z    = (const float*)d_in[0];
    const float* dW0  = (const float*)d_in[1];
    const float* db0  = (const float*)d_in[2];
    const float* dW1  = (const float*)d_in[3];
    const float* db1  = (const float*)d_in[4];
    const float* dWo  = (const float*)d_in[5];
    const float* dbo  = (const float*)d_in[6];
    const float* sW0  = (const float*)d_in[7];
    const float* sb0  = (const float*)d_in[8];
    const float* sW1  = (const float*)d_in[9];
    const float* sb1  = (const float*)d_in[10];
    const float* sWo  = (const float*)d_in[11];
    const float* sbo  = (const float*)d_in[12];
    const float* rW0  = (const float*)d_in[13];
    const float* rb0  = (const float*)d_in[14];
    const float* rW1  = (const float*)d_in[15];
    const float* rb1  = (const float*)d_in[16];
    const float* rWo  = (const float*)d_in[17];
    const float* rbo  = (const float*)d_in[18];
    const float* cb   = (const float*)d_in[19];

    float* out = (float*)d_out;
    float* ws = (float*)d_ws;           // [0..1024) cbnorm, [1024] loss accum

    prep_kernel<<<KCB / NT, NT, 0, stream>>>(cb, ws);

    const int grid = BROWS / RT;        // 8192 blocks
    net_kernel<0><<<grid, NT, 0, stream>>>(z, dW0, db0, dW1, db1, dWo, dbo,
                                           cb, ws, ws + KCB, out);
    net_kernel<1><<<grid, NT, 0, stream>>>(z, sW0, sb0, sW1, sb1, sWo, sbo,
                                           cb, ws, ws + KCB, out);
    net_kernel<2><<<grid, NT, 0, stream>>>(z, rW0, rb0, rW1, rb1, rWo, rbo,
                                           cb, ws, ws + KCB, out);

    fin_kernel<<<1, 64, 0, stream>>>(ws, out);
}

// Round 4
// 8077.729 us; speedup vs baseline: 1.4751x; 1.4751x over previous
//
#include <hip/hip_runtime.h>
#include <hip/hip_bf16.h>

#define NT 256          // threads per block
#define RT 16           // rows per block
#define AP 17           // activation LDS pitch (floats): act[col][AP] transposed, pitch 17 kills bank conflicts
#define WP 516          // weight-tile LDS pitch (floats): 512 + 4 keeps float4 alignment and spreads banks
#define INN 256
#define HIDN 512
#define LATN 256
#define KCB 1024
#define BROWS 131072

// d_out element offsets (fp32 elements)
#define SC_OFF   33554432ull            // B*LAT
#define RS_OFF   33685504ull
#define LOSS_OFF 33816576ull
#define IDS_OFF  33816577ull

// ---------------------------------------------------------------------------
// Tiled fp32 GEMM layer: act (transposed [col][row], pitch AP) -> act in-place.
// Accumulation: single accumulator per output, ascending-k FMA chain (numerics
// must stay bit-identical to the verified round-2 kernel).
// Software-pipelined: tile kt+1's weights are prefetched into registers while
// tile kt is being computed, so the barrier pair only brackets a ds_write.
// ---------------------------------------------------------------------------
template<int CPER>
__device__ __forceinline__ void gemm_layer(float* act, float* wbuf,
    const float* __restrict__ W, const float* __restrict__ bias,
    const int K, const bool do_relu, const int tid)
{
    constexpr int NCOLS = CPER * 64;
    constexpr int NE = (NCOLS * 8) / NT;     // staged elements per thread
    const int rgrp = tid & 3;
    const int c0   = (tid >> 2) * CPER;
    const int j0   = tid >> 3;               // staging col base
    const int kk0  = tid & 7;                // staging k-slice (constant per thread)

    float acc[4][CPER];
#pragma unroll
    for (int i = 0; i < 4; ++i)
#pragma unroll
        for (int m = 0; m < CPER; ++m) acc[i][m] = 0.f;

    // prefetch tile 0
    float pf[NE];
#pragma unroll
    for (int e = 0; e < NE; ++e)
        pf[e] = W[(size_t)(j0 + 32 * e) * K + kk0];

    const int ntiles = K >> 3;
    for (int kt = 0; kt < ntiles; ++kt) {
        __syncthreads();                     // everyone done reading wbuf
#pragma unroll
        for (int e = 0; e < NE; ++e)
            wbuf[kk0 * WP + j0 + 32 * e] = pf[e];
        __syncthreads();                     // tile visible
        // prefetch next tile; latency hidden under the compute below
        if (kt + 1 < ntiles) {
#pragma unroll
            for (int e = 0; e < NE; ++e)
                pf[e] = W[(size_t)(j0 + 32 * e) * K + ((kt + 1) << 3) + kk0];
        }
#pragma unroll
        for (int kk = 0; kk < 8; ++kk) {
            const int ka = (kt << 3) + kk;
            const float a0 = act[ka * AP + rgrp];
            const float a1 = act[ka * AP + rgrp + 4];
            const float a2 = act[ka * AP + rgrp + 8];
            const float a3 = act[ka * AP + rgrp + 12];
            const float* wr = &wbuf[kk * WP + c0];
#pragma unroll
            for (int q = 0; q < CPER / 4; ++q) {
                const float4 wv = *(const float4*)(wr + 4 * q);
                const float wz[4] = {wv.x, wv.y, wv.z, wv.w};
#pragma unroll
                for (int t = 0; t < 4; ++t) {
                    const float w = wz[t];
                    acc[0][4 * q + t] = fmaf(a0, w, acc[0][4 * q + t]);
                    acc[1][4 * q + t] = fmaf(a1, w, acc[1][4 * q + t]);
                    acc[2][4 * q + t] = fmaf(a2, w, acc[2][4 * q + t]);
                    acc[3][4 * q + t] = fmaf(a3, w, acc[3][4 * q + t]);
                }
            }
        }
    }
    __syncthreads();   // all reads of act done before overwriting
#pragma unroll
    for (int m = 0; m < CPER; ++m) {
        const float bv = bias[c0 + m];
#pragma unroll
        for (int i = 0; i < 4; ++i) {
            float v = __fadd_rn(acc[i][m], bv);   // single rounded add, like np
            if (do_relu) v = fmaxf(v, 0.f);
            act[(c0 + m) * AP + rgrp + 4 * i] = v;
        }
    }
    __syncthreads();
}

// numpy pairwise sum of squares over 256 contiguous elements (replicates
// np.sum(z*z, axis=1) rounding exactly): 2x128 blocks, 8 accumulators each.
__device__ __forceinline__ float np_sumsq_row(const float* act, const int r)
{
    float half[2];
#pragma unroll
    for (int h = 0; h < 2; ++h) {
        const int base = h * 128;
        float rr[8];
#pragma unroll
        for (int j = 0; j < 8; ++j) {
            const float v = act[(base + j) * AP + r];
            rr[j] = __fmul_rn(v, v);
        }
        for (int i = 8; i < 128; i += 8) {
#pragma unroll
            for (int j = 0; j < 8; ++j) {
                const float v = act[(base + i + j) * AP + r];
                rr[j] = __fadd_rn(rr[j], __fmul_rn(v, v));
            }
        }
        half[h] = __fadd_rn(
            __fadd_rn(__fadd_rn(rr[0], rr[1]), __fadd_rn(rr[2], rr[3])),
            __fadd_rn(__fadd_rn(rr[4], rr[5]), __fadd_rn(rr[6], rr[7])));
    }
    return __fadd_rn(half[0], half[1]);
}

// ---------------------------------------------------------------------------
// NET: 0 = decoder (+VQ distance/argmin/outputs/loss), 1 = scaler, 2 = redshift
// ---------------------------------------------------------------------------
template<int NET>
__global__ __launch_bounds__(NT, 3)
void net_kernel(const float* __restrict__ z,
                const float* __restrict__ W0, const float* __restrict__ b0,
                const float* __restrict__ W1, const float* __restrict__ b1,
                const float* __restrict__ Wo, const float* __restrict__ bo,
                const float* __restrict__ cb, const float* __restrict__ cbn,
                float* __restrict__ loss_ws,
                float* __restrict__ out)
{
    __shared__ __align__(16) float act[HIDN * AP];   // 34816 B
    __shared__ __align__(16) float wbuf[8 * WP];     // 16512 B
    __shared__ int idT[RT];
    __shared__ float sz2[RT];

    const int tid  = threadIdx.x;
    const int row0 = blockIdx.x * RT;

    // stage z tile transposed: act[c][r]
#pragma unroll
    for (int it = 0; it < RT; ++it)
        act[tid * AP + it] = z[(size_t)(row0 + it) * INN + tid];

    gemm_layer<8>(act, wbuf, W0, b0, INN,  true, tid);
    gemm_layer<8>(act, wbuf, W1, b1, HIDN, true, tid);

    if (NET == 0) {
        gemm_layer<4>(act, wbuf, Wo, bo, HIDN, false, tid);   // zl -> act[c][r], c<256

        // per-row sum(zl^2) with numpy-pairwise rounding
        if (tid < RT) sz2[tid] = np_sumsq_row(act, tid);
        __syncthreads();

        // ---- VQ distance, replicating np fp32 rounding:
        //      d2 = fl( fl(sumz2 - fl(2*dot)) + cn )
        const int rgrp = tid & 3;
        const int kgrp = tid >> 2;          // 64 k-groups x 8 k each per half
        const int cc0  = tid >> 7;          // cb staging: cc = cc0 + 2e
        const int k40  = (tid & 127) << 2;
        float bestv[4] = {1e30f, 1e30f, 1e30f, 1e30f};
        int   bestk[4] = {0, 0, 0, 0};

        // prefetch cb tile (kh=0, ct=0)
        float4 cpf[4];
#pragma unroll
        for (int e = 0; e < 4; ++e)
            cpf[e] = *(const float4*)&cb[(size_t)(cc0 + 2 * e) * KCB + k40];

        for (int kh = 0; kh < 2; ++kh) {
            float s[4][8];
#pragma unroll
            for (int i = 0; i < 4; ++i)
#pragma unroll
                for (int m = 0; m < 8; ++m) s[i][m] = 0.f;

            for (int ct = 0; ct < 32; ++ct) {
                __syncthreads();
#pragma unroll
                for (int e = 0; e < 4; ++e)
                    *(float4*)&wbuf[(cc0 + 2 * e) * WP + k40] = cpf[e];
                __syncthreads();
                // prefetch next cb tile (linear over kh,ct)
                const int nlin = (kh << 5) + ct + 1;
                if (nlin < 64) {
                    const int nct = nlin & 31, nkh = nlin >> 5;
#pragma unroll
                    for (int e = 0; e < 4; ++e)
                        cpf[e] = *(const float4*)&cb[
                            (size_t)(nct * 8 + cc0 + 2 * e) * KCB + (nkh << 9) + k40];
                }
#pragma unroll
                for (int cc = 0; cc < 8; ++cc) {
                    const int ca = ct * 8 + cc;
                    const float a0 = act[ca * AP + rgrp];
                    const float a1 = act[ca * AP + rgrp + 4];
                    const float a2 = act[ca * AP + rgrp + 8];
                    const float a3 = act[ca * AP + rgrp + 12];
                    const float* cr = &wbuf[cc * WP + (kgrp << 3)];
                    const float4 w0 = *(const float4*)cr;
                    const float4 w1 = *(const float4*)(cr + 4);
                    const float wz[8] = {w0.x, w0.y, w0.z, w0.w, w1.x, w1.y, w1.z, w1.w};
#pragma unroll
                    for (int m = 0; m < 8; ++m) {
                        s[0][m] = fmaf(a0, wz[m], s[0][m]);
                        s[1][m] = fmaf(a1, wz[m], s[1][m]);
                        s[2][m] = fmaf(a2, wz[m], s[2][m]);
                        s[3][m] = fmaf(a3, wz[m], s[3][m]);
                    }
                }
            }
            // fold into running argmin with np's exact rounding sequence
#pragma unroll
            for (int m = 0; m < 8; ++m) {
                const int kab = (kh << 9) + (kgrp << 3) + m;
                const float cn = cbn[kab];
#pragma unroll
                for (int i = 0; i < 4; ++i) {
                    const float t = __fsub_rn(sz2[rgrp + 4 * i],
                                              __fmul_rn(2.f, s[i][m]));
                    const float d = __fadd_rn(t, cn);
                    if (d < bestv[i]) { bestv[i] = d; bestk[i] = kab; }
                }
            }
        }

        // ---- cross-thread argmin reduce (wbuf reused as scratch)
        __syncthreads();
        float* rv = wbuf;
        int*   rk = (int*)(wbuf + 1024);
#pragma unroll
        for (int i = 0; i < 4; ++i) {
            rv[kgrp * 16 + rgrp + 4 * i] = bestv[i];
            rk[kgrp * 16 + rgrp + 4 * i] = bestk[i];
        }
        __syncthreads();
        if (tid < RT) {
            float bv = 1e30f; int bk = 0;
            for (int kg = 0; kg < 64; ++kg) {
                const float v = rv[kg * 16 + tid];
                const int   k = rk[kg * 16 + tid];
                if (v < bv || (v == bv && k < bk)) { bv = v; bk = k; }
            }
            idT[tid] = bk;
            out[IDS_OFF + row0 + tid] = (float)bk;
        }
        __syncthreads();

        // ---- epilogue: z_q_st = z_q (forward), loss partial
        float lsum = 0.f;
#pragma unroll
        for (int r = 0; r < RT; ++r) {
            const int id = idT[r];
            const float zv = act[tid * AP + r];
            const float q  = cb[(size_t)tid * KCB + id] - zv;
            out[(size_t)(row0 + r) * LATN + tid] = zv + q;
            lsum += q * q;
        }
        lsum += __shfl_down(lsum, 32);
        lsum += __shfl_down(lsum, 16);
        lsum += __shfl_down(lsum, 8);
        lsum += __shfl_down(lsum, 4);
        lsum += __shfl_down(lsum, 2);
        lsum += __shfl_down(lsum, 1);
        if ((tid & 63) == 0)
            atomicAdd(loss_ws, lsum * (1.0f / 33554432.0f));   // 1/(B*LAT)
    } else {
        // ---- out_dim == 1: out[r] = h2[r] . Wo + bo
        const int r  = tid & 15;
        const int kg = tid >> 4;
        float p = 0.f;
#pragma unroll
        for (int kk = 0; kk < 32; ++kk) {
            const int k = (kg << 5) + kk;
            p = fmaf(act[k * AP + r], Wo[k], p);
        }
        wbuf[kg * 16 + r] = p;
        __syncthreads();
        if (tid < RT) {
            float s2 = bo[0];
            for (int kg2 = 0; kg2 < 16; ++kg2) s2 += wbuf[kg2 * 16 + tid];
            if (NET == 2) s2 = fmaxf(s2, 0.f);
            const size_t off = (NET == 1) ? SC_OFF : RS_OFF;
            out[off + row0 + tid] = s2;
        }
    }
}

// cbnorm[k]: replicate np.sum(cb*cb, axis=0) — strided axis-0 reduction is
// SEQUENTIAL (no pairwise) over c ascending, squares rounded separately.
__global__ void prep_kernel(const float* __restrict__ cb, float* __restrict__ ws)
{
    const int k = blockIdx.x * NT + threadIdx.x;
    float a = 0.f;
    for (int c = 0; c < LATN; ++c) {
        const float v = cb[(size_t)c * KCB + k];
        a = __fadd_rn(a, __fmul_rn(v, v));
    }
    ws[k] = a;
    if (k == 0) ws[KCB] = 0.f;
}

__global__ void fin_kernel(const float* __restrict__ ws, float* __restrict__ out)
{
    if (threadIdx.x == 0) out[LOSS_OFF] = ws[KCB];
}

extern "C" void kernel_launch(void* const* d_in, const int* in_sizes, int n_in,
                              void* d_out, int out_size, void* d_ws, size_t ws_size,
                              hipStream_t stream)
{
    const float* z    = (const float*)d_in[0];
    const float* dW0  = (const float*)d_in[1];
    const float* db0  = (const float*)d_in[2];
    const float* dW1  = (const float*)d_in[3];
    const float* db1  = (const float*)d_in[4];
    const float* dWo  = (const float*)d_in[5];
    const float* dbo  = (const float*)d_in[6];
    const float* sW0  = (const float*)d_in[7];
    const float* sb0  = (const float*)d_in[8];
    const float* sW1  = (const float*)d_in[9];
    const float* sb1  = (const float*)d_in[10];
    const float* sWo  = (const float*)d_in[11];
    const float* sbo  = (const float*)d_in[12];
    const float* rW0  = (const float*)d_in[13];
    const float* rb0  = (const float*)d_in[14];
    const float* rW1  = (const float*)d_in[15];
    const float* rb1  = (const float*)d_in[16];
    const float* rWo  = (const float*)d_in[17];
    const float* rbo  = (const float*)d_in[18];
    const float* cb   = (const float*)d_in[19];

    float* out = (float*)d_out;
    float* ws = (float*)d_ws;           // [0..1024) cbnorm, [1024] loss accum

    prep_kernel<<<KCB / NT, NT, 0, stream>>>(cb, ws);

    const int grid = BROWS / RT;        // 8192 blocks
    net_kernel<0><<<grid, NT, 0, stream>>>(z, dW0, db0, dW1, db1, dWo, dbo,
                                           cb, ws, ws + KCB, out);
    net_kernel<1><<<grid, NT, 0, stream>>>(z, sW0, sb0, sW1, sb1, sWo, sbo,
                                           cb, ws, ws + KCB, out);
    net_kernel<2><<<grid, NT, 0, stream>>>(z, rW0, rb0, rW1, rb1, rWo, rbo,
                                           cb, ws, ws + KCB, out);

    fin_kernel<<<1, 64, 0, stream>>>(ws, out);
}